// Round 4
// baseline (182.484 us; speedup 1.0000x reference)
//
#include <hip/hip_runtime.h>
#include <math.h>

#define EMBED 512
#define NQ 8
#define SEQ 2048
#define NB 8
#define LOG2E 1.4426950408889634f

typedef float vfloat4 __attribute__((ext_vector_type(4)));  // clang vector: ok for nontemporal builtins

// ---------------------------------------------------------------------------
// k1: rotT[b][q][i] = sum_e x[b][i][e] * R[e][q]
// R transposed through LDS (stride 516 keeps rows 16B-aligned, conflict-free
// b128 reads). Thread (q = tid&7, rslot = tid>>3) does one K=512 dot with
// vfloat4; x loads 8-way lane-duplicated (one 128B L1 transaction per wave).
// HBM traffic = the 32 MiB x read ≈ 5.3 µs floor.
// ---------------------------------------------------------------------------
#define RPAD 516

__global__ __launch_bounds__(256) void qa_rot(
    const float* __restrict__ x, const float* __restrict__ R,
    float* __restrict__ rotT) {
    __shared__ float rt[NQ * RPAD];
#pragma unroll
    for (int m = 0; m < (EMBED * NQ) / 256; ++m) {
        int f = threadIdx.x + m * 256;
        rt[(f & 7) * RPAD + (f >> 3)] = R[f];
    }
    __syncthreads();

    const int q = threadIdx.x & 7;
    const int rslot = threadIdx.x >> 3;           // 0..31
    const int b = blockIdx.x >> 6;                // 64 blocks per batch
    const int i = ((blockIdx.x & 63) << 5) + rslot;

    const vfloat4* __restrict__ xr =
        (const vfloat4*)(x + ((size_t)b * SEQ + i) * EMBED);
    const vfloat4* __restrict__ rr = (const vfloat4*)(rt + q * RPAD);

    float acc = 0.f;
#pragma unroll 8
    for (int m = 0; m < EMBED / 4; ++m) {
        vfloat4 a = xr[m];
        vfloat4 r = rr[m];
        acc = fmaf(a.x, r.x, acc);
        acc = fmaf(a.y, r.y, acc);
        acc = fmaf(a.z, r.z, acc);
        acc = fmaf(a.w, r.w, acc);
    }
    rotT[(size_t)b * (NQ * SEQ) + (size_t)q * SEQ + i] = acc;
}

// ---------------------------------------------------------------------------
// k2: scores[b][i][j] = sigmoid(rot_i . rot_j) / rowsum — single pass,
// NO LDS. rotT is 512 KiB total -> L2/L3-resident; rj fragments are read
// straight from global as coalesced dwordx4 (1 KB/wave-instr, ~134 MB of
// cache traffic ~4 µs at L2 rate). No staging loop, no __syncthreads.
// __launch_bounds__(256,4) caps VGPRs at 128 (pv 64 + rj 32 + ri 16 + misc)
// -> 16 waves/CU / 4 blocks/CU, so store-burst blocks overlap compute
// blocks and the kernel rides the 21 µs HBM-write floor.
// Block = 4 waves; wave owns TI=2 rows; 8 rows/block; 256 blocks/batch.
// ---------------------------------------------------------------------------
#define K2_THREADS 256
#define TI 2
#define ROWS_PER_BLOCK 8    // 4 waves * TI

__global__ __launch_bounds__(K2_THREADS, 4) void qa_scores(
    const float* __restrict__ rotT, float* __restrict__ out) {
    const int b = blockIdx.x >> 8;                // 256 blocks per batch
    const int i0 = (blockIdx.x & 255) * ROWS_PER_BLOCK + (threadIdx.x >> 6) * TI;
    const int lane = threadIdx.x & 63;
    const float* __restrict__ rt = rotT + (size_t)b * (NQ * SEQ);

    // rot_i for this wave's 2 rows: wave-uniform addresses -> scalar loads.
    float ri[TI][NQ];
#pragma unroll
    for (int r = 0; r < TI; ++r)
#pragma unroll
        for (int q = 0; q < NQ; ++q)
            ri[r][q] = rt[q * SEQ + i0 + r];

    // 8 tiles of 256 j; lane owns j = t*256 + 4*lane .. +3.
    vfloat4 pv[8][TI];                             // 64 VGPRs of probs
    float rsum[TI] = {0.f, 0.f};

#pragma unroll
    for (int t = 0; t < 8; ++t) {
        vfloat4 rj[NQ];
#pragma unroll
        for (int q = 0; q < NQ; ++q)
            rj[q] = *((const vfloat4*)(rt + q * SEQ + t * 256) + lane);
#pragma unroll
        for (int r = 0; r < TI; ++r) {
            vfloat4 s = {0.f, 0.f, 0.f, 0.f};
#pragma unroll
            for (int q = 0; q < NQ; ++q) {
                s.x = fmaf(ri[r][q], rj[q].x, s.x);
                s.y = fmaf(ri[r][q], rj[q].y, s.y);
                s.z = fmaf(ri[r][q], rj[q].z, s.z);
                s.w = fmaf(ri[r][q], rj[q].w, s.w);
            }
            vfloat4 p;
            p.x = __builtin_amdgcn_rcpf(1.f + __builtin_amdgcn_exp2f(-s.x * LOG2E));
            p.y = __builtin_amdgcn_rcpf(1.f + __builtin_amdgcn_exp2f(-s.y * LOG2E));
            p.z = __builtin_amdgcn_rcpf(1.f + __builtin_amdgcn_exp2f(-s.z * LOG2E));
            p.w = __builtin_amdgcn_rcpf(1.f + __builtin_amdgcn_exp2f(-s.w * LOG2E));
            pv[t][r] = p;
            rsum[r] += (p.x + p.y) + (p.z + p.w);
        }
    }

    // Butterfly reduce rowsums over 64 lanes; keep inverse.
#pragma unroll
    for (int r = 0; r < TI; ++r) {
#pragma unroll
        for (int off = 32; off > 0; off >>= 1)
            rsum[r] += __shfl_xor(rsum[r], off);
        rsum[r] = __builtin_amdgcn_rcpf(rsum[r]);
    }

    // Normalize from registers and store (dwordx4, nontemporal).
#pragma unroll
    for (int r = 0; r < TI; ++r) {
        float* __restrict__ orow = out + ((size_t)b * SEQ + i0 + r) * SEQ;
#pragma unroll
        for (int t = 0; t < 8; ++t) {
            vfloat4 v = pv[t][r] * rsum[r];
            __builtin_nontemporal_store(v, (vfloat4*)(orow + t * 256) + lane);
        }
    }
}

// ---------------------------------------------------------------------------
extern "C" void kernel_launch(void* const* d_in, const int* in_sizes, int n_in,
                              void* d_out, int out_size, void* d_ws, size_t ws_size,
                              hipStream_t stream) {
    const float* x        = (const float*)d_in[0];  // (8, 2048, 512) fp32
    const float* rotation = (const float*)d_in[1];  // (512, 8) fp32
    float* out = (float*)d_out;                     // (8, 2048, 2048) fp32

    float* rotT = (float*)d_ws;                     // 8 x 8 x 2048 = 512 KiB

    qa_rot<<<NB * 64, 256, 0, stream>>>(x, rotation, rotT);
    qa_scores<<<NB * 256, K2_THREADS, 0, stream>>>(rotT, out);
}

// Round 5
// 181.602 us; speedup vs baseline: 1.0049x; 1.0049x over previous
//
#include <hip/hip_runtime.h>
#include <math.h>

#define EMBED 512
#define NQ 8
#define SEQ 2048
#define NB 8
#define LOG2E 1.4426950408889634f

typedef float vfloat4 __attribute__((ext_vector_type(4)));  // clang vector: ok for nontemporal builtins

// ---------------------------------------------------------------------------
// k1: rotT[b][q][i] = sum_e x[b][i][e] * R[e][q]
// R transposed through LDS (stride 516: 16B-aligned rows, conflict-free b128).
// Thread (q = tid&7, rslot = tid>>3) does one K=512 dot with vfloat4.
// 4 independent accumulator chains (x/y/z/w) — the single-acc version was
// latency-bound (512 dependent fmas x 4 cyc at 2 waves/SIMD).
// ---------------------------------------------------------------------------
#define RPAD 516

__global__ __launch_bounds__(256) void qa_rot(
    const float* __restrict__ x, const float* __restrict__ R,
    float* __restrict__ rotT) {
    __shared__ float rt[NQ * RPAD];
#pragma unroll
    for (int m = 0; m < (EMBED * NQ) / 256; ++m) {
        int f = threadIdx.x + m * 256;
        rt[(f & 7) * RPAD + (f >> 3)] = R[f];
    }
    __syncthreads();

    const int q = threadIdx.x & 7;
    const int rslot = threadIdx.x >> 3;           // 0..31
    const int b = blockIdx.x >> 6;                // 64 blocks per batch
    const int i = ((blockIdx.x & 63) << 5) + rslot;

    const vfloat4* __restrict__ xr =
        (const vfloat4*)(x + ((size_t)b * SEQ + i) * EMBED);
    const vfloat4* __restrict__ rr = (const vfloat4*)(rt + q * RPAD);

    vfloat4 acc = {0.f, 0.f, 0.f, 0.f};           // 4 independent chains
#pragma unroll 8
    for (int m = 0; m < EMBED / 4; ++m) {
        vfloat4 a = xr[m];
        vfloat4 r = rr[m];
        acc.x = fmaf(a.x, r.x, acc.x);
        acc.y = fmaf(a.y, r.y, acc.y);
        acc.z = fmaf(a.z, r.z, acc.z);
        acc.w = fmaf(a.w, r.w, acc.w);
    }
    rotT[(size_t)b * (NQ * SEQ) + (size_t)q * SEQ + i] =
        (acc.x + acc.y) + (acc.z + acc.w);
}

// ---------------------------------------------------------------------------
// k2: scores[b][i][j] = sigmoid(rot_i . rot_j) / rowsum — single pass, no
// LDS, NO launch_bounds occupancy cap (R4's cap at 128 VGPR sat exactly at
// the register demand -> suspected scratch spills; this round removes the
// cap as a spill-vs-traffic discriminator). rotT (512 KiB) is L2-resident;
// rj read as coalesced dwordx4. No __syncthreads -> waves free-run, store
// traffic spreads in time instead of bursting per block phase.
// Block = 4 waves; wave owns TI=2 rows; 8 rows/block; 256 blocks/batch.
// ---------------------------------------------------------------------------
#define K2_THREADS 256
#define TI 2
#define ROWS_PER_BLOCK 8    // 4 waves * TI

__global__ __launch_bounds__(K2_THREADS) void qa_scores(
    const float* __restrict__ rotT, float* __restrict__ out) {
    const int b = blockIdx.x >> 8;                // 256 blocks per batch
    const int i0 = (blockIdx.x & 255) * ROWS_PER_BLOCK + (threadIdx.x >> 6) * TI;
    const int lane = threadIdx.x & 63;
    const float* __restrict__ rt = rotT + (size_t)b * (NQ * SEQ);

    // rot_i for this wave's 2 rows (wave-uniform -> scalar loads).
    float ri[TI][NQ];
#pragma unroll
    for (int r = 0; r < TI; ++r)
#pragma unroll
        for (int q = 0; q < NQ; ++q)
            ri[r][q] = rt[q * SEQ + i0 + r];

    // 8 tiles of 256 j; lane owns j = t*256 + 4*lane .. +3.
    vfloat4 pv[8][TI];                             // 64 VGPRs of probs
    float rsum[TI] = {0.f, 0.f};

#pragma unroll
    for (int t = 0; t < 8; ++t) {
        vfloat4 rj[NQ];
#pragma unroll
        for (int q = 0; q < NQ; ++q)
            rj[q] = *((const vfloat4*)(rt + q * SEQ + t * 256) + lane);
#pragma unroll
        for (int r = 0; r < TI; ++r) {
            vfloat4 s = {0.f, 0.f, 0.f, 0.f};
#pragma unroll
            for (int q = 0; q < NQ; ++q) {
                s.x = fmaf(ri[r][q], rj[q].x, s.x);
                s.y = fmaf(ri[r][q], rj[q].y, s.y);
                s.z = fmaf(ri[r][q], rj[q].z, s.z);
                s.w = fmaf(ri[r][q], rj[q].w, s.w);
            }
            vfloat4 p;
            p.x = __builtin_amdgcn_rcpf(1.f + __builtin_amdgcn_exp2f(-s.x * LOG2E));
            p.y = __builtin_amdgcn_rcpf(1.f + __builtin_amdgcn_exp2f(-s.y * LOG2E));
            p.z = __builtin_amdgcn_rcpf(1.f + __builtin_amdgcn_exp2f(-s.z * LOG2E));
            p.w = __builtin_amdgcn_rcpf(1.f + __builtin_amdgcn_exp2f(-s.w * LOG2E));
            pv[t][r] = p;
            rsum[r] += (p.x + p.y) + (p.z + p.w);
        }
    }

    // Butterfly reduce rowsums over 64 lanes; keep inverse.
#pragma unroll
    for (int r = 0; r < TI; ++r) {
#pragma unroll
        for (int off = 32; off > 0; off >>= 1)
            rsum[r] += __shfl_xor(rsum[r], off);
        rsum[r] = __builtin_amdgcn_rcpf(rsum[r]);
    }

    // Normalize from registers and store (dwordx4, nontemporal).
#pragma unroll
    for (int r = 0; r < TI; ++r) {
        float* __restrict__ orow = out + ((size_t)b * SEQ + i0 + r) * SEQ;
#pragma unroll
        for (int t = 0; t < 8; ++t) {
            vfloat4 v = pv[t][r] * rsum[r];
            __builtin_nontemporal_store(v, (vfloat4*)(orow + t * 256) + lane);
        }
    }
}

// ---------------------------------------------------------------------------
extern "C" void kernel_launch(void* const* d_in, const int* in_sizes, int n_in,
                              void* d_out, int out_size, void* d_ws, size_t ws_size,
                              hipStream_t stream) {
    const float* x        = (const float*)d_in[0];  // (8, 2048, 512) fp32
    const float* rotation = (const float*)d_in[1];  // (512, 8) fp32
    float* out = (float*)d_out;                     // (8, 2048, 2048) fp32

    float* rotT = (float*)d_ws;                     // 8 x 8 x 2048 = 512 KiB

    qa_rot<<<NB * 64, 256, 0, stream>>>(x, rotation, rotT);
    qa_scores<<<NB * 256, K2_THREADS, 0, stream>>>(rotT, out);
}

// Round 6
// 171.145 us; speedup vs baseline: 1.0663x; 1.0611x over previous
//
#include <hip/hip_runtime.h>
#include <math.h>

#define EMBED 512
#define NQ 8
#define SEQ 2048
#define NB 8
#define LOG2E 1.4426950408889634f

typedef float vfloat4 __attribute__((ext_vector_type(4)));  // clang vector: ok for nontemporal builtins

// ---------------------------------------------------------------------------
// k1: rotT[b][q][i] = sum_e x[b][i][e] * R[e][q]
// R transposed through LDS (stride 516: 16B-aligned rows, conflict-free b128).
// Thread (q = tid&7, rslot = tid>>3) does one K=512 dot with vfloat4.
// 4 independent accumulator chains hide fma latency. Plain (cached) store of
// rotT — k2 re-reads it immediately, keep it in L2.
// ---------------------------------------------------------------------------
#define RPAD 516

__global__ __launch_bounds__(256) void qa_rot(
    const float* __restrict__ x, const float* __restrict__ R,
    float* __restrict__ rotT) {
    __shared__ float rt[NQ * RPAD];
#pragma unroll
    for (int m = 0; m < (EMBED * NQ) / 256; ++m) {
        int f = threadIdx.x + m * 256;
        rt[(f & 7) * RPAD + (f >> 3)] = R[f];
    }
    __syncthreads();

    const int q = threadIdx.x & 7;
    const int rslot = threadIdx.x >> 3;           // 0..31
    const int b = blockIdx.x >> 6;                // 64 blocks per batch
    const int i = ((blockIdx.x & 63) << 5) + rslot;

    const vfloat4* __restrict__ xr =
        (const vfloat4*)(x + ((size_t)b * SEQ + i) * EMBED);
    const vfloat4* __restrict__ rr = (const vfloat4*)(rt + q * RPAD);

    vfloat4 acc = {0.f, 0.f, 0.f, 0.f};           // 4 independent chains
#pragma unroll 8
    for (int m = 0; m < EMBED / 4; ++m) {
        vfloat4 a = xr[m];
        vfloat4 r = rr[m];
        acc.x = fmaf(a.x, r.x, acc.x);
        acc.y = fmaf(a.y, r.y, acc.y);
        acc.z = fmaf(a.z, r.z, acc.z);
        acc.w = fmaf(a.w, r.w, acc.w);
    }
    rotT[(size_t)b * (NQ * SEQ) + (size_t)q * SEQ + i] =
        (acc.x + acc.y) + (acc.z + acc.w);
}

// ---------------------------------------------------------------------------
// k2: scores[b][i][j] = sigmoid(rot_i . rot_j) / rowsum — single pass,
// LDS-staged (R3 structure, which beat no-LDS by 7 µs), but 512-thread
// blocks: 8 waves x TI=2 = 16 rows/block, 128 blocks/batch, grid 1024.
// 64 KiB LDS -> 2 blocks/CU -> 16 waves/CU (2x R3): store bursts of some
// waves overlap compute of others; staging traffic per row halves.
// __launch_bounds__(512,4) -> 128-VGPR cap; q-outer inner loop keeps rj
// live range at one vfloat4 so demand ~107 regs, no spill.
// ---------------------------------------------------------------------------
#define K2_THREADS 512
#define TI 2
#define ROWS_PER_BLOCK 16   // 8 waves * TI

__global__ __launch_bounds__(K2_THREADS, 4) void qa_scores(
    const float* __restrict__ rotT, float* __restrict__ out) {
    __shared__ float lds[NQ * SEQ];               // 64 KiB, [q][j]
    const int b = blockIdx.x >> 7;                // 128 blocks per batch
    const int i0blk = (blockIdx.x & 127) * ROWS_PER_BLOCK;
    const float* __restrict__ rt = rotT + (size_t)b * (NQ * SEQ);

    // Stage rotT[b] (16384 floats) cooperatively, coalesced 16B.
    {
        const vfloat4* __restrict__ src = (const vfloat4*)rt;
        vfloat4* dst = (vfloat4*)lds;
#pragma unroll
        for (int m = 0; m < (NQ * SEQ / 4) / K2_THREADS; ++m)
            dst[threadIdx.x + m * K2_THREADS] = src[threadIdx.x + m * K2_THREADS];
    }
    __syncthreads();

    const int wave = threadIdx.x >> 6;            // 0..7
    const int lane = threadIdx.x & 63;
    const int i0 = i0blk + wave * TI;

    // rot_i for this wave's 2 rows (broadcast LDS reads).
    float ri[TI][NQ];
#pragma unroll
    for (int r = 0; r < TI; ++r)
#pragma unroll
        for (int q = 0; q < NQ; ++q)
            ri[r][q] = lds[q * SEQ + i0 + r];

    // 8 tiles of 256 j; lane owns j = t*256 + 4*lane .. +3.
    vfloat4 pv[8][TI];                             // 64 VGPRs of probs
    float rsum[TI] = {0.f, 0.f};

#pragma unroll
    for (int t = 0; t < 8; ++t) {
        vfloat4 s[TI];
#pragma unroll
        for (int r = 0; r < TI; ++r) s[r] = (vfloat4){0.f, 0.f, 0.f, 0.f};
        // q-outer: one rj vfloat4 live at a time (register budget).
#pragma unroll
        for (int q = 0; q < NQ; ++q) {
            vfloat4 rj = *((const vfloat4*)(lds + q * SEQ + t * 256) + lane);
#pragma unroll
            for (int r = 0; r < TI; ++r) {
                s[r].x = fmaf(ri[r][q], rj.x, s[r].x);
                s[r].y = fmaf(ri[r][q], rj.y, s[r].y);
                s[r].z = fmaf(ri[r][q], rj.z, s[r].z);
                s[r].w = fmaf(ri[r][q], rj.w, s[r].w);
            }
        }
#pragma unroll
        for (int r = 0; r < TI; ++r) {
            vfloat4 p;
            p.x = __builtin_amdgcn_rcpf(1.f + __builtin_amdgcn_exp2f(-s[r].x * LOG2E));
            p.y = __builtin_amdgcn_rcpf(1.f + __builtin_amdgcn_exp2f(-s[r].y * LOG2E));
            p.z = __builtin_amdgcn_rcpf(1.f + __builtin_amdgcn_exp2f(-s[r].z * LOG2E));
            p.w = __builtin_amdgcn_rcpf(1.f + __builtin_amdgcn_exp2f(-s[r].w * LOG2E));
            pv[t][r] = p;
            rsum[r] += (p.x + p.y) + (p.z + p.w);
        }
    }

    // Butterfly reduce rowsums over 64 lanes; keep inverse.
#pragma unroll
    for (int r = 0; r < TI; ++r) {
#pragma unroll
        for (int off = 32; off > 0; off >>= 1)
            rsum[r] += __shfl_xor(rsum[r], off);
        rsum[r] = __builtin_amdgcn_rcpf(rsum[r]);
    }

    // Normalize from registers and store (dwordx4, nontemporal).
#pragma unroll
    for (int r = 0; r < TI; ++r) {
        float* __restrict__ orow = out + ((size_t)b * SEQ + i0 + r) * SEQ;
#pragma unroll
        for (int t = 0; t < 8; ++t) {
            vfloat4 v = pv[t][r] * rsum[r];
            __builtin_nontemporal_store(v, (vfloat4*)(orow + t * 256) + lane);
        }
    }
}

// ---------------------------------------------------------------------------
extern "C" void kernel_launch(void* const* d_in, const int* in_sizes, int n_in,
                              void* d_out, int out_size, void* d_ws, size_t ws_size,
                              hipStream_t stream) {
    const float* x        = (const float*)d_in[0];  // (8, 2048, 512) fp32
    const float* rotation = (const float*)d_in[1];  // (512, 8) fp32
    float* out = (float*)d_out;                     // (8, 2048, 2048) fp32

    float* rotT = (float*)d_ws;                     // 8 x 8 x 2048 = 512 KiB

    qa_rot<<<NB * 64, 256, 0, stream>>>(x, rotation, rotT);
    qa_scores<<<NB * 128, K2_THREADS, 0, stream>>>(rotT, out);
}